// Round 2
// baseline (318.060 us; speedup 1.0000x reference)
//
#include <hip/hip_runtime.h>
#include <hip/hip_bf16.h>
#include <stdint.h>

typedef __attribute__((ext_vector_type(8))) _Float16 f16x8;
typedef __attribute__((ext_vector_type(4))) float f32x4;

static constexpr int BATCH = 4;
static constexpr int SEQ = 4096;
static constexpr int DIM = 64;
static constexpr uint32_t N_ELEMS = 67108864u;          // 4*4096*4096
static constexpr uint32_t KEEP_THRESH = 0xCCCCCE00u;    // uniform(bits) < 0.8f

__device__ __forceinline__ void tf_round(uint32_t& x0, uint32_t& x1, int r) {
  x0 += x1;
  x1 = (x1 << r) | (x1 >> (32 - r));
  x1 ^= x0;
}

// JAX threefry2x32 with key (0, 42), partitionable path: bits = o0 ^ o1
__device__ __forceinline__ void threefry2x32(uint32_t c0, uint32_t c1,
                                             uint32_t& o0, uint32_t& o1) {
  const uint32_t k0 = 0u, k1 = 42u;
  const uint32_t k2 = 0x1BD11BDAu ^ k0 ^ k1;
  uint32_t x0 = c0 + k0, x1 = c1 + k1;
  tf_round(x0, x1, 13); tf_round(x0, x1, 15); tf_round(x0, x1, 26); tf_round(x0, x1, 6);
  x0 += k1; x1 += k2 + 1u;
  tf_round(x0, x1, 17); tf_round(x0, x1, 29); tf_round(x0, x1, 16); tf_round(x0, x1, 24);
  x0 += k2; x1 += k0 + 2u;
  tf_round(x0, x1, 13); tf_round(x0, x1, 15); tf_round(x0, x1, 26); tf_round(x0, x1, 6);
  x0 += k0; x1 += k1 + 3u;
  tf_round(x0, x1, 17); tf_round(x0, x1, 29); tf_round(x0, x1, 16); tf_round(x0, x1, 24);
  x0 += k1; x1 += k2 + 4u;
  tf_round(x0, x1, 13); tf_round(x0, x1, 15); tf_round(x0, x1, 26); tf_round(x0, x1, 6);
  x0 += k2; x1 += k0 + 5u;
  o0 = x0; o1 = x1;
}

__global__ __launch_bounds__(256) void maskgen_kernel(uint32_t* __restrict__ mask) {
  uint32_t gid = blockIdx.x * blockDim.x + threadIdx.x;
  uint32_t stride = gridDim.x * blockDim.x;   // multiple of 64
  uint32_t lane = threadIdx.x & 63u;
  for (uint32_t j = gid; j < N_ELEMS; j += stride) {
    uint32_t o0, o1;
    threefry2x32(0u, j, o0, o1);
    uint32_t bits = o0 ^ o1;
    bool keep = bits < KEEP_THRESH;
    unsigned long long bal = __ballot(keep);
    if ((lane & 31u) == 0u) {
      mask[j >> 5] = (uint32_t)(bal >> lane);   // lane 0 -> low word, lane 32 -> high word
    }
  }
}

__global__ __launch_bounds__(256) void attn_kernel(
    const float* __restrict__ Q, const float* __restrict__ K, const float* __restrict__ V,
    const uint32_t* __restrict__ mask, const uint32_t* __restrict__ scale_raw,
    float* __restrict__ Out)
{
  __shared__ __align__(16) _Float16 Khi[64 * 72];      // K-tile hi, row-major [k][d]
  __shared__ __align__(16) _Float16 Klo[64 * 72];      // K-tile lo (residual)
  __shared__ __align__(16) _Float16 Vld[64 * 72];      // V-tile, transposed [d][k]
  __shared__ __align__(16) _Float16 Pld[4][16 * 72];   // per-wave P transpose buffer

  const int b   = blockIdx.y;
  const int q0  = blockIdx.x * 64;
  const int tid = threadIdx.x;
  const int w    = tid >> 6;
  const int lane = tid & 63;
  const int l15  = lane & 15;
  const int l4   = lane >> 4;

  // scale_factor arrives as a 1-element array; dtype (int vs float) ambiguous -> decode bits
  float scale;
  {
    uint32_t sb = *scale_raw;
    int e = (int)((sb >> 23) & 0xFFu);
    if (sb == 0u) scale = 0.0f;
    else if (e == 0 || e == 255) scale = (float)(int)sb;
    else scale = __uint_as_float(sb);
  }

  const int qw = q0 + w * 16;   // this wave's 16 q-rows

  // Q A-fragments, split fp16 hi/lo, held in registers for the whole KV loop
  // A layout (16x16x32): row = lane&15, k = (lane>>4)*8 + j
  f16x8 aqh[2], aql[2];
#pragma unroll
  for (int c = 0; c < 2; ++c) {
    const float* qp = Q + ((size_t)(b * SEQ + qw + l15)) * DIM + l4 * 8 + 32 * c;
    f16x8 h, l;
#pragma unroll
    for (int j = 0; j < 8; ++j) {
      float f = qp[j];
      _Float16 fh = (_Float16)f;
      h[j] = fh;
      l[j] = (_Float16)(f - (float)fh);
    }
    aqh[c] = h; aql[c] = l;
  }

  // Online-softmax state: each lane owns rows (l4*4 + r), r=0..3
  float m_r[4], l_r[4];
  f32x4 Oacc[4];
#pragma unroll
  for (int r = 0; r < 4; ++r) { m_r[r] = -INFINITY; l_r[r] = 0.0f; }
#pragma unroll
  for (int n = 0; n < 4; ++n) Oacc[n] = f32x4{0.f, 0.f, 0.f, 0.f};

  for (int kb = 0; kb < SEQ / 64; ++kb) {
    const int kbase = kb * 64;
    __syncthreads();   // previous iteration's LDS reads done before overwrite
    // ---- stage K hi/lo (row-major fp16) and V (transposed fp16) into LDS ----
#pragma unroll
    for (int i = 0; i < 4; ++i) {
      int flat = tid + i * 256;         // float4 index within 64x64 tile
      int row = flat >> 4;              // 0..63 (k index)
      int col = (flat & 15) * 4;        // 0..60 (d index)
      const float* kp = K + ((size_t)(b * SEQ + kbase + row)) * DIM + col;
      const float* vp = V + ((size_t)(b * SEQ + kbase + row)) * DIM + col;
      float4 kf = *(const float4*)kp;
      float4 vf = *(const float4*)vp;
      _Float16 h0 = (_Float16)kf.x, h1 = (_Float16)kf.y,
               h2 = (_Float16)kf.z, h3 = (_Float16)kf.w;
      *(ushort4*)&Khi[row * 72 + col] = ushort4{
        (unsigned short)__builtin_bit_cast(unsigned short, h0),
        (unsigned short)__builtin_bit_cast(unsigned short, h1),
        (unsigned short)__builtin_bit_cast(unsigned short, h2),
        (unsigned short)__builtin_bit_cast(unsigned short, h3)};
      _Float16 l0 = (_Float16)(kf.x - (float)h0), l1 = (_Float16)(kf.y - (float)h1),
               l2 = (_Float16)(kf.z - (float)h2), l3 = (_Float16)(kf.w - (float)h3);
      *(ushort4*)&Klo[row * 72 + col] = ushort4{
        (unsigned short)__builtin_bit_cast(unsigned short, l0),
        (unsigned short)__builtin_bit_cast(unsigned short, l1),
        (unsigned short)__builtin_bit_cast(unsigned short, l2),
        (unsigned short)__builtin_bit_cast(unsigned short, l3)};
      Vld[(col + 0) * 72 + row] = (_Float16)vf.x;
      Vld[(col + 1) * 72 + row] = (_Float16)vf.y;
      Vld[(col + 2) * 72 + row] = (_Float16)vf.z;
      Vld[(col + 3) * 72 + row] = (_Float16)vf.w;
    }
    __syncthreads();

    // ---- S = scale * Q K^T via split fp16: qh*kh + qh*kl + ql*kh ----
    f32x4 s[4];
#pragma unroll
    for (int n = 0; n < 4; ++n) {
      f32x4 acc = f32x4{0.f, 0.f, 0.f, 0.f};
#pragma unroll
      for (int c = 0; c < 2; ++c) {
        int off = (16 * n + l15) * 72 + l4 * 8 + 32 * c;
        f16x8 bh = *(const f16x8*)&Khi[off];
        f16x8 bl = *(const f16x8*)&Klo[off];
        acc = __builtin_amdgcn_mfma_f32_16x16x32_f16(aqh[c], bh, acc, 0, 0, 0);
        acc = __builtin_amdgcn_mfma_f32_16x16x32_f16(aqh[c], bl, acc, 0, 0, 0);
        acc = __builtin_amdgcn_mfma_f32_16x16x32_f16(aql[c], bh, acc, 0, 0, 0);
      }
#pragma unroll
      for (int r = 0; r < 4; ++r) acc[r] *= scale;
      s[n] = acc;
    }

    // ---- dropout mask words: row qg, cols kbase..kbase+63 -> 2 uint32 words ----
    uint32_t mw0[4], mw1[4];
#pragma unroll
    for (int r = 0; r < 4; ++r) {
      int qg = qw + l4 * 4 + r;
      uint32_t wb = (((uint32_t)(b * SEQ + qg)) * (uint32_t)SEQ + (uint32_t)kbase) >> 5;
      mw0[r] = mask[wb];
      mw1[r] = mask[wb + 1];
    }

    // ---- online softmax: row max over 64 cols (4 n-tiles x 16 lanes) ----
    float mnew[4];
#pragma unroll
    for (int r = 0; r < 4; ++r) {
      mnew[r] = fmaxf(fmaxf(s[0][r], s[1][r]), fmaxf(s[2][r], s[3][r]));
#pragma unroll
      for (int off = 1; off < 16; off <<= 1)
        mnew[r] = fmaxf(mnew[r], __shfl_xor(mnew[r], off, 64));
    }

    float corr[4];
#pragma unroll
    for (int r = 0; r < 4; ++r) {
      float mn = fmaxf(m_r[r], mnew[r]);
      corr[r] = __expf(m_r[r] - mn);   // first iter: exp(-inf) = 0
      m_r[r] = mn;
      l_r[r] *= corr[r];
    }
#pragma unroll
    for (int n = 0; n < 4; ++n)
#pragma unroll
      for (int r = 0; r < 4; ++r) Oacc[n][r] *= corr[r];

    // ---- e = exp(s-m); denominator uses UNMASKED e; P (for PV) is masked ----
    float psum[4] = {0.f, 0.f, 0.f, 0.f};
    _Float16* pw = &Pld[w][0];
#pragma unroll
    for (int n = 0; n < 4; ++n) {
#pragma unroll
      for (int r = 0; r < 4; ++r) {
        float e = __expf(s[n][r] - m_r[r]);
        psum[r] += e;
        uint32_t word = (n < 2) ? mw0[r] : mw1[r];
        int bit = l15 + ((n & 1) << 4);
        float p = ((word >> bit) & 1u) ? e : 0.0f;
        pw[(l4 * 4 + r) * 72 + l15 + 16 * n] = (_Float16)p;   // transpose via LDS
      }
    }
#pragma unroll
    for (int r = 0; r < 4; ++r) {
#pragma unroll
      for (int off = 1; off < 16; off <<= 1)
        psum[r] += __shfl_xor(psum[r], off, 64);
      l_r[r] += psum[r];
    }

    // wave-local LDS ordering: P writes before P reads
    asm volatile("s_waitcnt lgkmcnt(0)" ::: "memory");
    __builtin_amdgcn_sched_barrier(0);

    // ---- PV: O += P[16x64] * V[64x64] ----
    f16x8 pa[2];
#pragma unroll
    for (int c = 0; c < 2; ++c)
      pa[c] = *(const f16x8*)&pw[l15 * 72 + l4 * 8 + 32 * c];
#pragma unroll
    for (int n = 0; n < 4; ++n) {
#pragma unroll
      for (int c = 0; c < 2; ++c) {
        f16x8 bv = *(const f16x8*)&Vld[(l15 + 16 * n) * 72 + l4 * 8 + 32 * c];
        Oacc[n] = __builtin_amdgcn_mfma_f32_16x16x32_f16(pa[c], bv, Oacc[n], 0, 0, 0);
      }
    }
  }

  // ---- epilogue: out = Onum / (L * keep_prob) ----
#pragma unroll
  for (int r = 0; r < 4; ++r) {
    float inv = 1.0f / (l_r[r] * 0.8f);
    int qg = qw + l4 * 4 + r;
    float* op = Out + ((size_t)(b * SEQ + qg)) * DIM + l15;
#pragma unroll
    for (int n = 0; n < 4; ++n) {
      op[16 * n] = Oacc[n][r] * inv;
    }
  }
}

extern "C" void kernel_launch(void* const* d_in, const int* in_sizes, int n_in,
                              void* d_out, int out_size, void* d_ws, size_t ws_size,
                              hipStream_t stream) {
  const float* Q = (const float*)d_in[0];
  const float* K = (const float*)d_in[1];
  const float* V = (const float*)d_in[2];
  const uint32_t* scale_raw = (const uint32_t*)d_in[3];
  uint32_t* mask = (uint32_t*)d_ws;       // 8,388,608 bytes of bitmask
  float* Out = (float*)d_out;

  maskgen_kernel<<<2048, 256, 0, stream>>>(mask);
  attn_kernel<<<dim3(SEQ / 64, BATCH), 256, 0, stream>>>(Q, K, V, mask, scale_raw, Out);
}

// Round 3
// 197.860 us; speedup vs baseline: 1.6075x; 1.6075x over previous
//
#include <hip/hip_runtime.h>
#include <hip/hip_bf16.h>
#include <stdint.h>

typedef __attribute__((ext_vector_type(8))) _Float16 f16x8;
typedef __attribute__((ext_vector_type(4))) float f32x4;

static constexpr int BATCH = 4;
static constexpr int SEQ = 4096;
static constexpr int DIM = 64;
static constexpr uint32_t KEEP_THRESH = 0xCCCCCE00u;   // uniform(bits) < 0.8f
static constexpr int NSPLIT = 4;
static constexpr int TILES_TOTAL = SEQ / 64;            // 64
static constexpr int TILES_PER_SPLIT = TILES_TOTAL / NSPLIT;

// workspace layout (split path): onum fp32 [4b][64qb][4s][64r][64d] then ml [pb][64r][2]
static constexpr size_t ONUM_BYTES = (size_t)BATCH * 64 * NSPLIT * 64 * 64 * 4;  // 16,777,216
static constexpr size_t ML_BYTES   = (size_t)BATCH * 64 * NSPLIT * 64 * 2 * 4;   //    524,288
static constexpr size_t WS_NEEDED  = ONUM_BYTES + ML_BYTES;

__device__ __forceinline__ uint32_t rotl32(uint32_t x, int r) {
  return __builtin_rotateleft32(x, (uint32_t)r);
}

// JAX threefry2x32, key (0,42), counter (0,j), partitionable fold o0^o1; keep iff < 0.8
__device__ __forceinline__ bool tf_keep(uint32_t j) {
  const uint32_t k1 = 42u;
  const uint32_t k2 = 0x1BD11BDAu ^ k1;       // 0x1BD11BE0
  uint32_t x1 = j + k1;
  uint32_t x0 = x1;                            // 0 + x1 (round-1 add, k0 = 0)
  x1 = rotl32(x1, 13) ^ x0;
  x0 += x1; x1 = rotl32(x1, 15) ^ x0;
  x0 += x1; x1 = rotl32(x1, 26) ^ x0;
  x0 += x1; x1 = rotl32(x1, 6)  ^ x0;
  x0 += k1;      x1 += k2 + 1u;
  x0 += x1; x1 = rotl32(x1, 17) ^ x0;
  x0 += x1; x1 = rotl32(x1, 29) ^ x0;
  x0 += x1; x1 = rotl32(x1, 16) ^ x0;
  x0 += x1; x1 = rotl32(x1, 24) ^ x0;
  x0 += k2;      x1 += 2u;                     // k0 + 2
  x0 += x1; x1 = rotl32(x1, 13) ^ x0;
  x0 += x1; x1 = rotl32(x1, 15) ^ x0;
  x0 += x1; x1 = rotl32(x1, 26) ^ x0;
  x0 += x1; x1 = rotl32(x1, 6)  ^ x0;
  /* x0 += k0 (=0) */ x1 += k1 + 3u;           // 45
  x0 += x1; x1 = rotl32(x1, 17) ^ x0;
  x0 += x1; x1 = rotl32(x1, 29) ^ x0;
  x0 += x1; x1 = rotl32(x1, 16) ^ x0;
  x0 += x1; x1 = rotl32(x1, 24) ^ x0;
  x0 += k1;      x1 += k2 + 4u;
  x0 += x1; x1 = rotl32(x1, 13) ^ x0;
  x0 += x1; x1 = rotl32(x1, 15) ^ x0;
  x0 += x1; x1 = rotl32(x1, 26) ^ x0;
  x0 += x1; x1 = rotl32(x1, 6)  ^ x0;
  x0 += k2;      x1 += 5u;                     // k0 + 5
  return (x0 ^ x1) < KEEP_THRESH;
}

template<bool PARTIAL>
__global__ __launch_bounds__(256, 4) void attn_kernel(
    const float* __restrict__ Q, const float* __restrict__ K, const float* __restrict__ V,
    const uint32_t* __restrict__ scale_raw,
    float* __restrict__ Out, float* __restrict__ onum, float* __restrict__ ml)
{
  __shared__ __align__(16) _Float16 Khi[64 * 72];      // K-tile hi, row-major [k][d]
  __shared__ __align__(16) _Float16 Klo[64 * 72];      // K-tile lo (residual)
  __shared__ __align__(16) _Float16 Vld[64 * 72];      // V-tile, transposed [d][k]
  __shared__ __align__(16) _Float16 Pld[4][16 * 72];   // per-wave P transpose buffer

  const int b   = blockIdx.y;
  const int q0  = blockIdx.x * 64;
  const int tid = threadIdx.x;
  const int w    = tid >> 6;
  const int lane = tid & 63;
  const int l15  = lane & 15;
  const int l4   = lane >> 4;

  // scale_factor: 1-element array, dtype ambiguous (int vs float) -> decode bits
  float scale;
  {
    uint32_t sb = *scale_raw;
    int e = (int)((sb >> 23) & 0xFFu);
    if (sb == 0u) scale = 0.0f;
    else if (e == 0 || e == 255) scale = (float)(int)sb;
    else scale = __uint_as_float(sb);
  }

  const int qw = q0 + w * 16;   // this wave's 16 q-rows

  // per-row threefry row-base: j = (b*SEQ + qrow)*SEQ + col   (loop-invariant)
  uint32_t rcb[4];
#pragma unroll
  for (int r = 0; r < 4; ++r)
    rcb[r] = ((uint32_t)(b * SEQ + qw + l4 * 4 + r)) * (uint32_t)SEQ;

  // Q A-fragments, split fp16 hi/lo, in registers for the whole KV loop
  f16x8 aqh[2], aql[2];
#pragma unroll
  for (int c = 0; c < 2; ++c) {
    const float* qp = Q + ((size_t)(b * SEQ + qw + l15)) * DIM + l4 * 8 + 32 * c;
    f16x8 h, l;
#pragma unroll
    for (int j = 0; j < 8; ++j) {
      float f = qp[j];
      _Float16 fh = (_Float16)f;
      h[j] = fh;
      l[j] = (_Float16)(f - (float)fh);
    }
    aqh[c] = h; aql[c] = l;
  }

  float m_r[4], l_r[4];
  f32x4 Oacc[4];
#pragma unroll
  for (int r = 0; r < 4; ++r) { m_r[r] = -INFINITY; l_r[r] = 0.0f; }
#pragma unroll
  for (int n = 0; n < 4; ++n) Oacc[n] = f32x4{0.f, 0.f, 0.f, 0.f};

  const int t0 = PARTIAL ? (int)blockIdx.z * TILES_PER_SPLIT : 0;
  const int nt = PARTIAL ? TILES_PER_SPLIT : TILES_TOTAL;

  for (int kt = 0; kt < nt; ++kt) {
    const int kbase = (t0 + kt) * 64;
    __syncthreads();
    // ---- stage K hi/lo (row-major fp16) and V (transposed fp16) into LDS ----
#pragma unroll
    for (int i = 0; i < 4; ++i) {
      int flat = tid + i * 256;
      int row = flat >> 4;
      int col = (flat & 15) * 4;
      const float* kp = K + ((size_t)(b * SEQ + kbase + row)) * DIM + col;
      const float* vp = V + ((size_t)(b * SEQ + kbase + row)) * DIM + col;
      float4 kf = *(const float4*)kp;
      float4 vf = *(const float4*)vp;
      _Float16 h0 = (_Float16)kf.x, h1 = (_Float16)kf.y,
               h2 = (_Float16)kf.z, h3 = (_Float16)kf.w;
      *(ushort4*)&Khi[row * 72 + col] = ushort4{
        __builtin_bit_cast(unsigned short, h0), __builtin_bit_cast(unsigned short, h1),
        __builtin_bit_cast(unsigned short, h2), __builtin_bit_cast(unsigned short, h3)};
      _Float16 l0 = (_Float16)(kf.x - (float)h0), l1 = (_Float16)(kf.y - (float)h1),
               l2 = (_Float16)(kf.z - (float)h2), l3 = (_Float16)(kf.w - (float)h3);
      *(ushort4*)&Klo[row * 72 + col] = ushort4{
        __builtin_bit_cast(unsigned short, l0), __builtin_bit_cast(unsigned short, l1),
        __builtin_bit_cast(unsigned short, l2), __builtin_bit_cast(unsigned short, l3)};
      Vld[(col + 0) * 72 + row] = (_Float16)vf.x;
      Vld[(col + 1) * 72 + row] = (_Float16)vf.y;
      Vld[(col + 2) * 72 + row] = (_Float16)vf.z;
      Vld[(col + 3) * 72 + row] = (_Float16)vf.w;
    }
    __syncthreads();

    // ---- S = scale * Q K^T via split fp16: qh*kh + qh*kl + ql*kh ----
    f32x4 s[4];
#pragma unroll
    for (int n = 0; n < 4; ++n) {
      f32x4 acc = f32x4{0.f, 0.f, 0.f, 0.f};
#pragma unroll
      for (int c = 0; c < 2; ++c) {
        int off = (16 * n + l15) * 72 + l4 * 8 + 32 * c;
        f16x8 bh = *(const f16x8*)&Khi[off];
        f16x8 bl = *(const f16x8*)&Klo[off];
        acc = __builtin_amdgcn_mfma_f32_16x16x32_f16(aqh[c], bh, acc, 0, 0, 0);
        acc = __builtin_amdgcn_mfma_f32_16x16x32_f16(aqh[c], bl, acc, 0, 0, 0);
        acc = __builtin_amdgcn_mfma_f32_16x16x32_f16(aql[c], bh, acc, 0, 0, 0);
      }
#pragma unroll
      for (int r = 0; r < 4; ++r) acc[r] *= scale;
      s[n] = acc;
    }

    // ---- fused dropout mask: 16 threefry evals (independent VALU, hides MFMA latency)
    uint32_t kbits = 0;
#pragma unroll
    for (int n = 0; n < 4; ++n) {
      uint32_t cb = (uint32_t)(kbase + l15 + 16 * n);
#pragma unroll
      for (int r = 0; r < 4; ++r) {
        if (tf_keep(rcb[r] + cb)) kbits |= (1u << (n * 4 + r));
      }
    }

    // ---- online softmax: row max over 64 cols ----
    float mnew[4];
#pragma unroll
    for (int r = 0; r < 4; ++r) {
      mnew[r] = fmaxf(fmaxf(s[0][r], s[1][r]), fmaxf(s[2][r], s[3][r]));
#pragma unroll
      for (int off = 1; off < 16; off <<= 1)
        mnew[r] = fmaxf(mnew[r], __shfl_xor(mnew[r], off, 64));
    }

    float corr[4];
#pragma unroll
    for (int r = 0; r < 4; ++r) {
      float mn = fmaxf(m_r[r], mnew[r]);
      corr[r] = __expf(m_r[r] - mn);
      m_r[r] = mn;
      l_r[r] *= corr[r];
    }
#pragma unroll
    for (int n = 0; n < 4; ++n)
#pragma unroll
      for (int r = 0; r < 4; ++r) Oacc[n][r] *= corr[r];

    // ---- e = exp(s-m); denom uses UNMASKED e; P (for PV) is masked ----
    float psum[4] = {0.f, 0.f, 0.f, 0.f};
    _Float16* pw = &Pld[w][0];
#pragma unroll
    for (int n = 0; n < 4; ++n) {
#pragma unroll
      for (int r = 0; r < 4; ++r) {
        float e = __expf(s[n][r] - m_r[r]);
        psum[r] += e;
        float p = ((kbits >> (n * 4 + r)) & 1u) ? e : 0.0f;
        pw[(l4 * 4 + r) * 72 + l15 + 16 * n] = (_Float16)p;
      }
    }
#pragma unroll
    for (int r = 0; r < 4; ++r) {
#pragma unroll
      for (int off = 1; off < 16; off <<= 1)
        psum[r] += __shfl_xor(psum[r], off, 64);
      l_r[r] += psum[r];
    }

    // wave-local LDS ordering: P writes before P reads
    asm volatile("s_waitcnt lgkmcnt(0)" ::: "memory");
    __builtin_amdgcn_sched_barrier(0);

    // ---- PV: O += P[16x64] * V[64x64] ----
    f16x8 pa[2];
#pragma unroll
    for (int c = 0; c < 2; ++c)
      pa[c] = *(const f16x8*)&pw[l15 * 72 + l4 * 8 + 32 * c];
#pragma unroll
    for (int n = 0; n < 4; ++n) {
#pragma unroll
      for (int c = 0; c < 2; ++c) {
        f16x8 bv = *(const f16x8*)&Vld[(l15 + 16 * n) * 72 + l4 * 8 + 32 * c];
        Oacc[n] = __builtin_amdgcn_mfma_f32_16x16x32_f16(pa[c], bv, Oacc[n], 0, 0, 0);
      }
    }
  }

  if (PARTIAL) {
    // write raw partials: Onum (relative to running max m_r) + per-row (m, l)
    const int pb = ((b * 64 + (int)blockIdx.x) * NSPLIT + (int)blockIdx.z);
    float* op = onum + (size_t)pb * 4096;
#pragma unroll
    for (int r = 0; r < 4; ++r) {
      int row64 = w * 16 + l4 * 4 + r;
#pragma unroll
      for (int n = 0; n < 4; ++n)
        op[row64 * 64 + l15 + 16 * n] = Oacc[n][r];
      if (l15 == 0) {
        ml[(size_t)pb * 128 + row64 * 2 + 0] = m_r[r];
        ml[(size_t)pb * 128 + row64 * 2 + 1] = l_r[r];
      }
    }
  } else {
#pragma unroll
    for (int r = 0; r < 4; ++r) {
      float inv = 1.0f / (l_r[r] * 0.8f);
      int qg = qw + l4 * 4 + r;
      float* op = Out + ((size_t)(b * SEQ + qg)) * DIM + l15;
#pragma unroll
      for (int n = 0; n < 4; ++n)
        op[16 * n] = Oacc[n][r] * inv;
    }
  }
}

__global__ __launch_bounds__(256) void combine_kernel(
    const float* __restrict__ onum, const float* __restrict__ ml, float* __restrict__ Out)
{
  const int w = threadIdx.x >> 6;
  const int lane = threadIdx.x & 63;
  const int rid = blockIdx.x * 4 + w;          // 0..16383
  const int b = rid >> 12;
  const int qrow = rid & 4095;
  const int qb = qrow >> 6;
  const int r64 = qrow & 63;
  const int pb0 = (b * 64 + qb) * NSPLIT;

  float m[NSPLIT], l[NSPLIT];
  float M = -INFINITY;
#pragma unroll
  for (int s = 0; s < NSPLIT; ++s) {
    m[s] = ml[(size_t)(pb0 + s) * 128 + r64 * 2 + 0];
    l[s] = ml[(size_t)(pb0 + s) * 128 + r64 * 2 + 1];
    M = fmaxf(M, m[s]);
  }
  float L = 0.0f, acc = 0.0f;
#pragma unroll
  for (int s = 0; s < NSPLIT; ++s) {
    float sc = __expf(m[s] - M);
    L += l[s] * sc;
    acc += onum[(size_t)(pb0 + s) * 4096 + r64 * 64 + lane] * sc;
  }
  Out[(size_t)rid * 64 + lane] = acc / (L * 0.8f);
}

extern "C" void kernel_launch(void* const* d_in, const int* in_sizes, int n_in,
                              void* d_out, int out_size, void* d_ws, size_t ws_size,
                              hipStream_t stream) {
  const float* Q = (const float*)d_in[0];
  const float* K = (const float*)d_in[1];
  const float* V = (const float*)d_in[2];
  const uint32_t* scale_raw = (const uint32_t*)d_in[3];
  float* Out = (float*)d_out;

  if (ws_size >= WS_NEEDED) {
    float* onum = (float*)d_ws;
    float* ml = (float*)((char*)d_ws + ONUM_BYTES);
    attn_kernel<true><<<dim3(64, BATCH, NSPLIT), 256, 0, stream>>>(
        Q, K, V, scale_raw, nullptr, onum, ml);
    combine_kernel<<<SEQ * BATCH / 4, 256, 0, stream>>>(onum, ml, Out);
  } else {
    attn_kernel<false><<<dim3(64, BATCH, 1), 256, 0, stream>>>(
        Q, K, V, scale_raw, Out, nullptr, nullptr);
  }
}